// Round 6
// baseline (456.580 us; speedup 1.0000x reference)
//
#include <hip/hip_runtime.h>
#include <hip/hip_bf16.h>
#include <math.h>

__device__ __forceinline__ unsigned f2u(float f) {
    unsigned b = __float_as_uint(f);
    return b ^ ((unsigned)((int)b >> 31) | 0x80000000u);
}
__device__ __forceinline__ float u2f(unsigned u) {
    unsigned b = (u & 0x80000000u) ? (u ^ 0x80000000u) : ~u;
    return __uint_as_float(b);
}

// wave-level exact k=16 radix select over 256 values (4 per lane).
__device__ __forceinline__ void radix16(unsigned u0, unsigned u1, unsigned u2, unsigned u3,
                                        unsigned& T, int& kk) {
    unsigned prefix = 0; int k = 16;
    for (int b = 31; b >= 0; --b) {
        unsigned hi = (prefix >> b) | 1u;
        int cnt = __popcll(__ballot((u0 >> b) == hi))
                + __popcll(__ballot((u1 >> b) == hi))
                + __popcll(__ballot((u2 >> b) == hi))
                + __popcll(__ballot((u3 >> b) == hi));
        if (cnt >= k) prefix |= (1u << b); else k -= cnt;
    }
    T = prefix; kk = k;
}

// ---------------- Kernel 1: q = x @ Wq^T ----------------
__global__ __launch_bounds__(256) void k1_gemm(const float* __restrict__ A,
                                               const float* __restrict__ B,
                                               float* __restrict__ C) {
    __shared__ float As[16][128];
    __shared__ float Bs[16][128];
    int t  = threadIdx.x;
    int tx = t & 15, ty = t >> 4;
    int m0 = blockIdx.y * 128, n0 = blockIdx.x * 128;
    float acc[8][8] = {};
    for (int k0 = 0; k0 < 512; k0 += 16) {
#pragma unroll
        for (int i = 0; i < 2; ++i) {
            int u   = t * 2 + i;
            int row = u >> 2;
            int kc  = (u & 3) << 2;
            float4 av = *(const float4*)&A[(m0 + row) * 512 + k0 + kc];
            float4 bv = *(const float4*)&B[(n0 + row) * 512 + k0 + kc];
            As[kc + 0][row] = av.x; As[kc + 1][row] = av.y; As[kc + 2][row] = av.z; As[kc + 3][row] = av.w;
            Bs[kc + 0][row] = bv.x; Bs[kc + 1][row] = bv.y; Bs[kc + 2][row] = bv.z; Bs[kc + 3][row] = bv.w;
        }
        __syncthreads();
#pragma unroll
        for (int kk = 0; kk < 16; ++kk) {
            float4 a0 = *(const float4*)&As[kk][ty * 8];
            float4 a1 = *(const float4*)&As[kk][ty * 8 + 4];
            float4 b0 = *(const float4*)&Bs[kk][tx * 8];
            float4 b1 = *(const float4*)&Bs[kk][tx * 8 + 4];
            float a[8] = {a0.x, a0.y, a0.z, a0.w, a1.x, a1.y, a1.z, a1.w};
            float b[8] = {b0.x, b0.y, b0.z, b0.w, b1.x, b1.y, b1.z, b1.w};
#pragma unroll
            for (int i = 0; i < 8; ++i)
#pragma unroll
                for (int j = 0; j < 8; ++j) acc[i][j] += a[i] * b[j];
        }
        __syncthreads();
    }
#pragma unroll
    for (int i = 0; i < 8; ++i) {
        int m = m0 + ty * 8 + i;
        float4 o0; o0.x = acc[i][0]; o0.y = acc[i][1]; o0.z = acc[i][2]; o0.w = acc[i][3];
        float4 o1; o1.x = acc[i][4]; o1.y = acc[i][5]; o1.z = acc[i][6]; o1.w = acc[i][7];
        *(float4*)&C[m * 4096 + n0 + tx * 8]     = o0;
        *(float4*)&C[m * 4096 + n0 + tx * 8 + 4] = o1;
    }
}

// ---------------- Kernel 2: sim + radix top16 + combine + radix top16 + softmax ----------------
// grid: 2(c)*8(h)*32(ntile 32) = 512 blocks, 256 threads.
// Wave wv -> (p = wv>>1, nh = wv&1), 16 q-rows each; acc[16][4] in registers.
// q read directly from global via wave-uniform pointer (scalar/L1 broadcast).
// Keys double-buffered in LDS (2 x 18 KB, KROW=9 odd stride), 1 barrier/chunk.
#define KROW 9
#define PSTRIDE (256 * KROW)     // floats per p within a buffer
#define BUFSTRIDE (2 * PSTRIDE)  // floats per buffer
__global__ __launch_bounds__(256) void k2_scores(const float* __restrict__ q,
                                                 const float* __restrict__ keys,
                                                 int* __restrict__ widx,
                                                 float* __restrict__ wcoef) {
    int bid = blockIdx.x;
    int cc = bid & 1;
    int h  = (bid >> 1) & 7;
    int n0 = (bid >> 4) * 32;

    __shared__ float K_s[2][2][PSTRIDE];   // 36 KB: [buf][p][k*KROW + d]
    float (*sx_s)[32][16] = (float (*)[32][16]) &K_s[0][0][0];
    int   (*ix_s)[32][16] = (int   (*)[32][16])(&K_s[0][0][0] + 2 * 32 * 16);

    int t = threadIdx.x;
    int wv = t >> 6, ln = t & 63;
    int wvu = __builtin_amdgcn_readfirstlane(wv);
    int pu  = wvu >> 1;
    int nhu = wvu & 1;
    unsigned long long lt = (1ull << ln) - 1ull;

    // wave-uniform q base: rows pu*1024 + n0 + nhu*16 .. +15
    const float* qw = q + ((size_t)(pu * 1024 + n0 + nhu * 16) * 4096 + cc * 2048 + h * 256);

    float acc[16][4];
#pragma unroll
    for (int n = 0; n < 16; ++n)
#pragma unroll
        for (int j = 0; j < 4; ++j) acc[n][j] = 0.f;

    // staging: chunk = 2p x 256k x 8d floats = 1024 float4; 4 per thread
    int v0 = t, v1 = t + 256, v2 = t + 512, v3 = t + 768;
    int pp0 = v0 >> 9, k_0 = (v0 >> 1) & 255, s0 = v0 & 1;
    int pp1 = v1 >> 9, k_1 = (v1 >> 1) & 255, s1 = v1 & 1;
    int pp2 = v2 >> 9, k_2 = (v2 >> 1) & 255, s2 = v2 & 1;
    int pp3 = v3 >> 9, k_3 = (v3 >> 1) & 255, s3 = v3 & 1;
    const float* g0 = &keys[(size_t)(((h * 256 + k_0) * 2) + pp0) * 256 + s0 * 4];
    const float* g1 = &keys[(size_t)(((h * 256 + k_1) * 2) + pp1) * 256 + s1 * 4];
    const float* g2 = &keys[(size_t)(((h * 256 + k_2) * 2) + pp2) * 256 + s2 * 4];
    const float* g3 = &keys[(size_t)(((h * 256 + k_3) * 2) + pp3) * 256 + s3 * 4];
    int o0 = pp0 * PSTRIDE + k_0 * KROW + s0 * 4;
    int o1 = pp1 * PSTRIDE + k_1 * KROW + s1 * 4;
    int o2 = pp2 * PSTRIDE + k_2 * KROW + s2 * 4;
    int o3 = pp3 * PSTRIDE + k_3 * KROW + s3 * 4;
    float* lbase = &K_s[0][0][0];
    const float* kbase = &K_s[0][0][0] + pu * PSTRIDE;

    // prologue: chunk 0 -> buf0; preload chunk 1
    float4 st0 = *(const float4*)&g0[0];
    float4 st1 = *(const float4*)&g1[0];
    float4 st2 = *(const float4*)&g2[0];
    float4 st3 = *(const float4*)&g3[0];
    *(float4*)(lbase + o0) = st0;
    *(float4*)(lbase + o1) = st1;
    *(float4*)(lbase + o2) = st2;
    *(float4*)(lbase + o3) = st3;
    st0 = *(const float4*)&g0[8];
    st1 = *(const float4*)&g1[8];
    st2 = *(const float4*)&g2[8];
    st3 = *(const float4*)&g3[8];
    __syncthreads();

    for (int ch = 0; ch < 32; ++ch) {
        const float* rb = kbase + (ch & 1) * BUFSTRIDE;
#pragma unroll
        for (int s = 0; s < 2; ++s) {
            float4 k0 = *(const float4*)&rb[(ln      ) * KROW + s * 4];
            float4 k1 = *(const float4*)&rb[(ln +  64) * KROW + s * 4];
            float4 k2 = *(const float4*)&rb[(ln + 128) * KROW + s * 4];
            float4 k3 = *(const float4*)&rb[(ln + 192) * KROW + s * 4];
#pragma unroll
            for (int n = 0; n < 16; ++n) {
                float4 qv = *(const float4*)&qw[(size_t)n * 4096 + ch * 8 + s * 4];  // uniform
                acc[n][0] += qv.x * k0.x + qv.y * k0.y + qv.z * k0.z + qv.w * k0.w;
                acc[n][1] += qv.x * k1.x + qv.y * k1.y + qv.z * k1.z + qv.w * k1.w;
                acc[n][2] += qv.x * k2.x + qv.y * k2.y + qv.z * k2.z + qv.w * k2.w;
                acc[n][3] += qv.x * k3.x + qv.y * k3.y + qv.z * k3.z + qv.w * k3.w;
            }
        }
        if (ch < 31) {
            float* wb = lbase + ((ch + 1) & 1) * BUFSTRIDE;
            *(float4*)(wb + o0) = st0;
            *(float4*)(wb + o1) = st1;
            *(float4*)(wb + o2) = st2;
            *(float4*)(wb + o3) = st3;
            if (ch < 30) {
                st0 = *(const float4*)&g0[(ch + 2) * 8];
                st1 = *(const float4*)&g1[(ch + 2) * 8];
                st2 = *(const float4*)&g2[(ch + 2) * 8];
                st3 = *(const float4*)&g3[(ch + 2) * 8];
            }
            __syncthreads();
        }
    }
    // stage-1 writes go to float offsets [0,2048) = buf0 region; waves still in
    // ch=31 read only buf1 ([4608,9216)) -> disjoint, no barrier needed here.

    // ---- top-16 per (pu, row): radix select + ballot compaction; key id = ln + 64*slot ----
#pragma unroll
    for (int n = 0; n < 16; ++n) {
        int nn = nhu * 16 + n;
        unsigned u0 = f2u(acc[n][0]), u1 = f2u(acc[n][1]);
        unsigned u2 = f2u(acc[n][2]), u3 = f2u(acc[n][3]);
        unsigned T; int kk;
        radix16(u0, u1, u2, u3, T, kk);
        int base = 0;
#define TK1_GT(J, UJ, VJ) { unsigned long long m = __ballot(UJ > T);            \
        if (UJ > T) { int pos = base + __popcll(m & lt);                        \
            sx_s[pu][nn][pos] = VJ; ix_s[pu][nn][pos] = ln + 64 * J; }          \
        base += __popcll(m); }
        TK1_GT(0, u0, acc[n][0]); TK1_GT(1, u1, acc[n][1]);
        TK1_GT(2, u2, acc[n][2]); TK1_GT(3, u3, acc[n][3]);
#undef TK1_GT
#define TK1_EQ(J, UJ, VJ) { unsigned long long m = __ballot(UJ == T);           \
        int r = __popcll(m & lt);                                               \
        if ((UJ == T) && r < kk) { sx_s[pu][nn][base + r] = VJ;                 \
            ix_s[pu][nn][base + r] = ln + 64 * J; }                             \
        int cn = __popcll(m); int tk = cn < kk ? cn : kk;                       \
        base += tk; kk -= tk; }
        TK1_EQ(0, u0, acc[n][0]); TK1_EQ(1, u1, acc[n][1]);
        TK1_EQ(2, u2, acc[n][2]); TK1_EQ(3, u3, acc[n][3]);
#undef TK1_EQ
    }
    __syncthreads();

    // ---- combine 16x16, radix top-16, softmax: 8 tasks per wave ----
    for (int task = wv * 8; task < wv * 8 + 8; ++task) {
        int n = task;
        int t0 = ln, t1 = ln + 64, t2 = ln + 128, t3 = ln + 192;
        float vc0 = sx_s[0][n][t0 >> 4] + sx_s[1][n][t0 & 15];
        float vc1 = sx_s[0][n][t1 >> 4] + sx_s[1][n][t1 & 15];
        float vc2 = sx_s[0][n][t2 >> 4] + sx_s[1][n][t2 & 15];
        float vc3 = sx_s[0][n][t3 >> 4] + sx_s[1][n][t3 & 15];
        unsigned u0 = f2u(vc0), u1 = f2u(vc1), u2 = f2u(vc2), u3 = f2u(vc3);
        unsigned T; int kk;
        radix16(u0, u1, u2, u3, T, kk);
        float Tf = u2f(T);

        bool w0 = u0 > T, w1 = u1 > T, w2 = u2 > T, w3 = u3 > T;
        int q0 = 0, q1 = 0, q2 = 0, q3 = 0;
        int base = 0;
        { unsigned long long m = __ballot(w0); q0 = base + __popcll(m & lt); base += __popcll(m); }
        { unsigned long long m = __ballot(w1); q1 = base + __popcll(m & lt); base += __popcll(m); }
        { unsigned long long m = __ballot(w2); q2 = base + __popcll(m & lt); base += __popcll(m); }
        { unsigned long long m = __ballot(w3); q3 = base + __popcll(m & lt); base += __popcll(m); }
#define CMB_EQ(UJ, WJ, QJ) { unsigned long long m = __ballot(UJ == T);          \
        int r = __popcll(m & lt);                                               \
        if ((UJ == T) && r < kk) { WJ = true; QJ = base + r; }                  \
        int cn = __popcll(m); int tk = cn < kk ? cn : kk;                       \
        base += tk; kk -= tk; }
        CMB_EQ(u0, w0, q0); CMB_EQ(u1, w1, q1); CMB_EQ(u2, w2, q2); CMB_EQ(u3, w3, q3);
#undef CMB_EQ

        float e0 = 0.f, e1 = 0.f, e2 = 0.f, e3 = 0.f;
        int id0 = 0, id1 = 0, id2 = 0, id3 = 0;
        float es = 0.f;
        if (w0) { e0 = __expf(vc0 - Tf); es += e0; id0 = ix_s[0][n][t0 >> 4] * 256 + ix_s[1][n][t0 & 15]; }
        if (w1) { e1 = __expf(vc1 - Tf); es += e1; id1 = ix_s[0][n][t1 >> 4] * 256 + ix_s[1][n][t1 & 15]; }
        if (w2) { e2 = __expf(vc2 - Tf); es += e2; id2 = ix_s[0][n][t2 >> 4] * 256 + ix_s[1][n][t2 & 15]; }
        if (w3) { e3 = __expf(vc3 - Tf); es += e3; id3 = ix_s[0][n][t3 >> 4] * 256 + ix_s[1][n][t3 & 15]; }
        for (int s = 1; s < 64; s <<= 1) es += __shfl_xor(es, s);
        float inv = 1.f / es;

        int off = ((cc * 1024 + n0 + n) * 8 + h) * 16;
        if (w0) { wcoef[off + q0] = e0 * inv; widx[off + q0] = id0; }
        if (w1) { wcoef[off + q1] = e1 * inv; widx[off + q1] = id1; }
        if (w2) { wcoef[off + q2] = e2 * inv; widx[off + q2] = id2; }
        if (w3) { wcoef[off + q3] = e3 * inv; widx[off + q3] = id3; }
    }
}

// ---------------- Kernel 3: gather experts, gelu, weighted mix ----------------
__global__ __launch_bounds__(256) void k3_experts(const float* __restrict__ x,
                                                  const float* __restrict__ w_down,
                                                  const float* __restrict__ w_up,
                                                  const int* __restrict__ widx,
                                                  const float* __restrict__ wcoef,
                                                  float* __restrict__ out) {
    int bid = blockIdx.x;
    int c = bid >> 10, n = bid & 1023;
    int t = threadIdx.x, wv = t >> 6, ln = t & 63;
    __shared__ float wacc[4][512];

    const float* xrow = &x[(c * 1024 + n) * 512];
    float xr[8], oacc[8];
    {
        float4 xa = *(const float4*)&xrow[ln * 8];
        float4 xb = *(const float4*)&xrow[ln * 8 + 4];
        xr[0] = xa.x; xr[1] = xa.y; xr[2] = xa.z; xr[3] = xa.w;
        xr[4] = xb.x; xr[5] = xb.y; xr[6] = xb.z; xr[7] = xb.w;
    }
#pragma unroll
    for (int j = 0; j < 8; ++j) oacc[j] = 0.f;

    const int base = (c * 1024 + n) * 128;
    for (int e = wv * 32; e < wv * 32 + 32; ++e) {
        int   idx = widx[base + e];
        float wgt = wcoef[base + e];
        const float* dr = &w_down[(long)idx * 512 + ln * 8];
        float4 da = *(const float4*)&dr[0];
        float4 db = *(const float4*)&dr[4];
        float part = da.x * xr[0] + da.y * xr[1] + da.z * xr[2] + da.w * xr[3]
                   + db.x * xr[4] + db.y * xr[5] + db.z * xr[6] + db.w * xr[7];
        for (int s = 1; s < 64; s <<= 1) part += __shfl_xor(part, s);
        float hv = part;
        float coef = 0.5f * hv * (1.f + erff(hv * 0.70710678118654752f)) * wgt;
        const float* ur = &w_up[(long)idx * 512 + ln * 8];
        float4 ua = *(const float4*)&ur[0];
        float4 ub = *(const float4*)&ur[4];
        oacc[0] += coef * ua.x; oacc[1] += coef * ua.y; oacc[2] += coef * ua.z; oacc[3] += coef * ua.w;
        oacc[4] += coef * ub.x; oacc[5] += coef * ub.y; oacc[6] += coef * ub.z; oacc[7] += coef * ub.w;
    }
#pragma unroll
    for (int j = 0; j < 8; ++j) wacc[wv][ln * 8 + j] = oacc[j];
    __syncthreads();

    float* orow = &out[(c * 1024 + n) * 512];
    for (int d = t; d < 512; d += 256)
        orow[d] = wacc[0][d] + wacc[1][d] + wacc[2][d] + wacc[3][d];
}

extern "C" void kernel_launch(void* const* d_in, const int* in_sizes, int n_in,
                              void* d_out, int out_size, void* d_ws, size_t ws_size,
                              hipStream_t stream) {
    const float* x      = (const float*)d_in[0];
    const float* Wq     = (const float*)d_in[1];
    const float* keys   = (const float*)d_in[2];
    const float* w_down = (const float*)d_in[3];
    const float* w_up   = (const float*)d_in[4];
    float* out = (float*)d_out;

    char* ws = (char*)d_ws;
    float* q     = (float*)ws;                               // 32 MiB
    int*   widx  = (int*)(ws + 2048UL * 4096 * 4);           // 1 MiB
    float* wcoef = (float*)(ws + 2048UL * 4096 * 4 + 262144UL * 4);

    k1_gemm<<<dim3(32, 16), 256, 0, stream>>>(x, Wq, q);
    k2_scores<<<512, 256, 0, stream>>>(q, keys, widx, wcoef);
    k3_experts<<<2048, 256, 0, stream>>>(x, w_down, w_up, widx, wcoef, out);
}